// Round 6
// baseline (845.655 us; speedup 1.0000x reference)
//
#include <hip/hip_runtime.h>
#include <cmath>

// Tree constants (complete 4-ary tree, depth 7)
constexpr int N_NODES = 21845;
constexpr int N_INT   = 5461;   // internal nodes (levels 0..6)
constexpr int HID     = 512;

typedef short  short8  __attribute__((ext_vector_type(8)));
typedef float  floatx4 __attribute__((ext_vector_type(4)));

// fp32 -> bf16 bit pattern, round-to-nearest-even
__device__ __forceinline__ unsigned short f2bf(float f) {
    unsigned int u = __float_as_uint(f);
    u += 0x7fffu + ((u >> 16) & 1u);
    return (unsigned short)(u >> 16);
}

// ================= prep_a: cast x, W_iou, W_f to bf16 (contiguous dst) =================
__global__ void prep_a_kernel(const float* __restrict__ x,
                              const float* __restrict__ W_iou,
                              const float* __restrict__ W_f,
                              unsigned short* __restrict__ dstb)
{
    const size_t C0 = (size_t)N_INT * 512 / 4;
    const size_t C1 = C0 + 1536 * 512 / 4;
    const size_t C2 = C1 + 512 * 512 / 4;
    size_t i = (size_t)blockIdx.x * blockDim.x + threadIdx.x;
    const size_t stride = (size_t)gridDim.x * blockDim.x;
    for (; i < C2; i += stride) {
        const float* src; size_t off;
        if (i < C0)      { src = x;     off = i; }
        else if (i < C1) { src = W_iou; off = i - C0; }
        else             { src = W_f;   off = i - C1; }
        float4 v = ((const float4*)src)[off];
        ushort4 o;
        o.x = f2bf(v.x); o.y = f2bf(v.y); o.z = f2bf(v.z); o.w = f2bf(v.w);
        ((ushort4*)dstb)[i] = o;
    }
}

// ================= 128x128 bf16 MFMA GEMM tile (K=512), m97-style =================
#define GLD_LDS(g, l) __builtin_amdgcn_global_load_lds( \
    (const __attribute__((address_space(1))) void*)(g), \
    (__attribute__((address_space(3))) void*)(l), 16, 0, 0)

__device__ __forceinline__ void gemm_tile_128(
    const unsigned short* __restrict__ A, int Arows,
    const unsigned short* __restrict__ B,
    const float* __restrict__ bias,
    float* __restrict__ C, int ldc,
    int bm, int bn)
{
    __shared__ short8 AsV[1024];   // 128 rows x 8 chunks (16B) = 16 KB
    __shared__ short8 BsV[1024];

    const int tid  = threadIdx.x;
    const int wave = tid >> 6;
    const int lane = tid & 63;
    const int quad = lane >> 4;
    const int lr   = lane & 15;
    const int wr = (wave >> 1) * 64;
    const int wc = (wave & 1) * 64;

    floatx4 acc[4][4];
    #pragma unroll
    for (int i = 0; i < 4; ++i)
        #pragma unroll
        for (int j = 0; j < 4; ++j)
            acc[i][j] = (floatx4){0.f, 0.f, 0.f, 0.f};

    int s_row[4], s_gk[4];
    #pragma unroll
    for (int it = 0; it < 4; ++it) {
        int c = it * 256 + wave * 64 + lane;
        s_row[it] = c >> 3;
        s_gk[it]  = (c & 7) ^ (s_row[it] & 7);
    }

    for (int k0 = 0; k0 < 512; k0 += 64) {
        #pragma unroll
        for (int it = 0; it < 4; ++it) {
            int row = s_row[it];
            int gm = bm + row; if (gm >= Arows) gm = Arows - 1;
            GLD_LDS(A + (size_t)gm * 512 + k0 + s_gk[it] * 8, &AsV[it * 256 + wave * 64]);
            int gn = bn + row;
            GLD_LDS(B + (size_t)gn * 512 + k0 + s_gk[it] * 8, &BsV[it * 256 + wave * 64]);
        }
        __syncthreads();

        #pragma unroll
        for (int kc = 0; kc < 2; ++kc) {
            short8 af[4], bfr[4];
            const int q = kc * 4 + quad;
            #pragma unroll
            for (int mt = 0; mt < 4; ++mt) {
                int row = wr + mt * 16 + lr;
                af[mt] = AsV[row * 8 + (q ^ (row & 7))];
            }
            #pragma unroll
            for (int nt = 0; nt < 4; ++nt) {
                int row = wc + nt * 16 + lr;
                bfr[nt] = BsV[row * 8 + (q ^ (row & 7))];
            }
            #pragma unroll
            for (int mt = 0; mt < 4; ++mt)
                #pragma unroll
                for (int nt = 0; nt < 4; ++nt)
                    acc[mt][nt] = __builtin_amdgcn_mfma_f32_16x16x32_bf16(
                        af[mt], bfr[nt], acc[mt][nt], 0, 0, 0);
        }
        __syncthreads();
    }

    #pragma unroll
    for (int mt = 0; mt < 4; ++mt) {
        #pragma unroll
        for (int r = 0; r < 4; ++r) {
            int gm = bm + wr + mt * 16 + quad * 4 + r;
            if (gm >= Arows) continue;
            #pragma unroll
            for (int nt = 0; nt < 4; ++nt) {
                int gn = bn + wc + nt * 16 + lr;
                float v = acc[mt][nt][r];
                if (bias) v += bias[gn];
                C[(size_t)gm * ldc + gn] = v;
            }
        }
    }
}

// ================= fused W-GEMM dispatch: wx_iou (5461 rows) + wx_f (1365 rows) =================
__global__ __launch_bounds__(256) void wgemm_kernel(
    const unsigned short* __restrict__ xb,
    const unsigned short* __restrict__ Wib,
    const unsigned short* __restrict__ Wfb,
    const float* __restrict__ b_iou, const float* __restrict__ b_f,
    float* __restrict__ wx_iou, float* __restrict__ wx_f)
{
    int b = blockIdx.x;
    if (b < 516) {  // 43 m-tiles x 12 n-tiles
        gemm_tile_128(xb, N_INT, Wib, b_iou, wx_iou, 1536, (b / 12) * 128, (b % 12) * 128);
    } else {        // 11 m-tiles x 4 n-tiles (only levels 5..0 need wx_f)
        int b2 = b - 516;
        gemm_tile_128(xb, 1365, Wfb, b_f, wx_f, 512, (b2 / 4) * 128, (b2 % 4) * 128);
    }
}

// ================= combine6: level-6 combine + folded U-cast + leaf zero-fill =================
__global__ __launch_bounds__(512) void combine6_kernel(
    const float* __restrict__ wx_iou,
    const float* __restrict__ U_iou, const float* __restrict__ U_f,
    float* __restrict__ h_out, float* __restrict__ c_out,
    unsigned short* __restrict__ h_bf, unsigned short* __restrict__ hs_out,
    unsigned short* __restrict__ Ub_dst,     // Uib then Ufb, contiguous
    float* __restrict__ h_leaf, float* __restrict__ c_leaf)
{
    __shared__ float4 hsbuf[512];
    const int k  = threadIdx.x >> 7;
    const int jg = threadIdx.x & 127;
    const int j4 = jg << 2;

    for (int tp = blockIdx.x; tp < 1024; tp += gridDim.x) {
        const int n = 1365 + 4 * tp + k;
        const float* wrow = wx_iou + (size_t)n * 1536 + j4;
        float4 iv = *(const float4*)(wrow);
        float4 ov = *(const float4*)(wrow + 512);
        float4 uv = *(const float4*)(wrow + 1024);
        float4 cn, hn; ushort4 hb;
        #pragma unroll
        for (int c = 0; c < 4; ++c) {
            float ig = 1.f / (1.f + expf(-((float*)&iv)[c]));
            float og = 1.f / (1.f + expf(-((float*)&ov)[c]));
            float ug = tanhf(((float*)&uv)[c]);
            float cv2 = ig * ug;                 // children are leaves: c_ch = 0
            float hv = og * tanhf(cv2);
            ((float*)&cn)[c] = cv2;
            ((float*)&hn)[c] = hv;
            ((unsigned short*)&hb)[c] = f2bf(hv);
        }
        *(float4*)(c_out + (size_t)n * 512 + j4) = cn;
        *(float4*)(h_out + (size_t)n * 512 + j4) = hn;
        *(ushort4*)(h_bf + (size_t)n * 512 + j4) = hb;
        hsbuf[threadIdx.x] = hn;
        __syncthreads();
        if (threadIdx.x < 128) {
            float4 s0 = hsbuf[jg], s1 = hsbuf[128 + jg], s2 = hsbuf[256 + jg], s3 = hsbuf[384 + jg];
            ushort4 ho;
            #pragma unroll
            for (int c = 0; c < 4; ++c)
                ((unsigned short*)&ho)[c] =
                    f2bf(((float*)&s0)[c] + ((float*)&s1)[c] + ((float*)&s2)[c] + ((float*)&s3)[c]);
            *(ushort4*)(hs_out + (size_t)tp * 512 + j4) = ho;
        }
        __syncthreads();
    }

    // folded independent work: cast U_iou/U_f to bf16, zero leaf h/c rows
    const size_t CU0 = (size_t)1536 * 512 / 4;
    const size_t CU  = CU0 + (size_t)512 * 512 / 4;
    const size_t Z   = (size_t)(N_NODES - N_INT) * HID / 4;
    const size_t total = CU + 2 * Z;
    const float4 zz = {0.f, 0.f, 0.f, 0.f};
    for (size_t i = (size_t)blockIdx.x * blockDim.x + threadIdx.x; i < total;
         i += (size_t)gridDim.x * blockDim.x) {
        if (i < CU) {
            const float* src; size_t off;
            if (i < CU0) { src = U_iou; off = i; }
            else         { src = U_f;   off = i - CU0; }
            float4 v = ((const float4*)src)[off];
            ushort4 o;
            o.x = f2bf(v.x); o.y = f2bf(v.y); o.z = f2bf(v.z); o.w = f2bf(v.w);
            ((ushort4*)Ub_dst)[i] = o;
        } else {
            size_t z = i - CU;
            if (z < Z) ((float4*)h_leaf)[z] = zz;
            else       ((float4*)c_leaf)[z - Z] = zz;
        }
    }
}

// ================= direct-from-global MFMA tile: 16x64 over K=512 =================
__device__ __forceinline__ void direct_tile_16x64(
    const unsigned short* __restrict__ A, int Arows,
    const unsigned short* __restrict__ B,
    float* __restrict__ C, int ldc,
    int m0, int n0)
{
    const int lane = threadIdx.x & 63;
    const int quad = lane >> 4;
    const int lr   = lane & 15;
    int am = m0 + lr; if (am >= Arows) am = Arows - 1;   // clamp (store-masked)
    const unsigned short* ap = A + (size_t)am * 512 + quad * 8;
    const unsigned short* bp = B + (size_t)(n0 + lr) * 512 + quad * 8;

    floatx4 acc[4];
    #pragma unroll
    for (int j = 0; j < 4; ++j) acc[j] = (floatx4){0.f, 0.f, 0.f, 0.f};

    #pragma unroll
    for (int k0 = 0; k0 < 512; k0 += 32) {
        short8 af = *(const short8*)(ap + k0);
        #pragma unroll
        for (int j = 0; j < 4; ++j) {
            short8 bf = *(const short8*)(bp + (size_t)j * 16 * 512 + k0);
            acc[j] = __builtin_amdgcn_mfma_f32_16x16x32_bf16(af, bf, acc[j], 0, 0, 0);
        }
    }

    #pragma unroll
    for (int j = 0; j < 4; ++j) {
        #pragma unroll
        for (int r = 0; r < 4; ++r) {
            int gm = m0 + quad * 4 + r;
            if (gm < Arows) C[(size_t)gm * ldc + n0 + j * 16 + lr] = acc[j][r];
        }
    }
}

// ================= combine body for one (node n, j4) with U terms =================
__device__ __forceinline__ void combine_item(
    const float* __restrict__ wx_iou, const float* __restrict__ wx_f,
    const float* __restrict__ ioud, const float* __restrict__ fd,
    const float* __restrict__ c_child,
    float* __restrict__ h_out, float* __restrict__ c_out,
    unsigned short* __restrict__ h_bf,
    int n, int t, int j4, float4* hn_out)
{
    const float* wrow = wx_iou + (size_t)n * 1536 + j4;
    float4 iv = *(const float4*)(wrow);
    float4 ov = *(const float4*)(wrow + 512);
    float4 uv = *(const float4*)(wrow + 1024);
    const float* drow = ioud + (size_t)t * 1536 + j4;
    float4 a  = *(const float4*)(drow);
    float4 b  = *(const float4*)(drow + 512);
    float4 u2 = *(const float4*)(drow + 1024);
    float4 wf = *(const float4*)(wx_f + (size_t)n * 512 + j4);
    float4 fc = {0.f, 0.f, 0.f, 0.f};
    #pragma unroll
    for (int c = 0; c < 4; ++c) {
        ((float*)&iv)[c] += ((float*)&a)[c];
        ((float*)&ov)[c] += ((float*)&b)[c];
        ((float*)&uv)[c] += ((float*)&u2)[c];
    }
    #pragma unroll
    for (int q = 0; q < 4; ++q) {
        float4 f  = *(const float4*)(fd + (size_t)(4 * t + q) * 512 + j4);
        float4 cv = *(const float4*)(c_child + (size_t)(4 * t + q) * 512 + j4);
        #pragma unroll
        for (int c = 0; c < 4; ++c)
            ((float*)&fc)[c] += (((float*)&wf)[c] + ((float*)&f)[c]) * ((float*)&cv)[c];
    }
    float4 cn, hn; ushort4 hb;
    #pragma unroll
    for (int c = 0; c < 4; ++c) {
        float ig = 1.f / (1.f + expf(-((float*)&iv)[c]));
        float og = 1.f / (1.f + expf(-((float*)&ov)[c]));
        float ug = tanhf(((float*)&uv)[c]);
        float cv2 = ig * ug + ((float*)&fc)[c];
        float hv = og * tanhf(cv2);
        ((float*)&cn)[c] = cv2;
        ((float*)&hn)[c] = hv;
        ((unsigned short*)&hb)[c] = f2bf(hv);
    }
    *(float4*)(c_out + (size_t)n * 512 + j4) = cn;
    *(float4*)(h_out + (size_t)n * 512 + j4) = hn;
    *(ushort4*)(h_bf + (size_t)n * 512 + j4) = hb;
    *hn_out = hn;
}

// ================= fused level kernel: block owns 16 nodes, GEMM + combine =================
// grid = nl/16 blocks, 512 threads (8 waves).
__global__ __launch_bounds__(512) void fused_level_kernel(
    const float* __restrict__ wx_iou, const float* __restrict__ wx_f,
    const unsigned short* __restrict__ Uib, const unsigned short* __restrict__ Ufb,
    const unsigned short* __restrict__ hs_in,    // nl rows
    const unsigned short* __restrict__ hch_bf,   // h_bf + cb*512 (4nl rows)
    const float* __restrict__ c_child,           // c_out + cb*512
    float* __restrict__ ioud, float* __restrict__ fd,
    float* __restrict__ h_out, float* __restrict__ c_out,
    unsigned short* __restrict__ h_bf, unsigned short* __restrict__ hs_out,
    int s, int nl)
{
    const int b = blockIdx.x;
    const int wave = threadIdx.x >> 6;

    // phase 1: GEMMs for this block's 16 nodes (24 iou tiles + 32 f tiles)
    for (int tt = wave; tt < 56; tt += 8) {
        if (tt < 24) {
            direct_tile_16x64(hs_in, nl, Uib, ioud, 1536, 16 * b, tt * 64);
        } else {
            int ft = tt - 24;
            direct_tile_16x64(hch_bf, 4 * nl, Ufb, fd, 512,
                              64 * b + (ft >> 3) * 16, (ft & 7) * 64);
        }
    }
    __syncthreads();

    // phase 2: combine 16 nodes (4 sibling groups), emit 4 parent h_sums
    __shared__ float4 hsbuf[512];
    const int k  = threadIdx.x >> 7;
    const int jg = threadIdx.x & 127;
    const int j4 = jg << 2;
    for (int g = 0; g < 4; ++g) {
        const int gp = 4 * b + g;
        const int t  = 4 * gp + k;
        float4 hn;
        combine_item(wx_iou, wx_f, ioud, fd, c_child, h_out, c_out, h_bf,
                     s + t, t, j4, &hn);
        hsbuf[threadIdx.x] = hn;
        __syncthreads();
        if (threadIdx.x < 128) {
            float4 s0 = hsbuf[jg], s1 = hsbuf[128 + jg], s2 = hsbuf[256 + jg], s3 = hsbuf[384 + jg];
            ushort4 ho;
            #pragma unroll
            for (int c = 0; c < 4; ++c)
                ((unsigned short*)&ho)[c] =
                    f2bf(((float*)&s0)[c] + ((float*)&s1)[c] + ((float*)&s2)[c] + ((float*)&s3)[c]);
            *(ushort4*)(hs_out + (size_t)gp * 512 + j4) = ho;
        }
        __syncthreads();
    }
}

// ================= tail3: levels 2,1,0 in one single-workgroup kernel =================
__global__ __launch_bounds__(1024) void tail3_kernel(
    const float* __restrict__ wx_iou, const float* __restrict__ wx_f,
    const unsigned short* __restrict__ Uib, const unsigned short* __restrict__ Ufb,
    float* __restrict__ ioud, float* __restrict__ fd,
    float* __restrict__ h_out, float* __restrict__ c_out,
    unsigned short* __restrict__ h_bf,
    unsigned short* __restrict__ hsA, unsigned short* __restrict__ hsB)
{
    __shared__ float4 hbuf[16 * 128];   // 32 KB
    const int wave = threadIdx.x >> 6;
    const int tid  = threadIdx.x;

    const int SS[3] = {5, 1, 0};
    const int NL[3] = {16, 4, 1};
    const int CB[3] = {21, 5, 1};
    const unsigned short* hs_in[3] = {hsB, hsA, hsB};
    unsigned short* hs_o[3] = {hsA, hsB, nullptr};

    for (int li = 0; li < 3; ++li) {
        const int s = SS[li], nl = NL[li], cb = CB[li];

        // GEMM phase
        const int mF = (4 * nl + 15) >> 4;
        const int nT = 24 + mF * 8;
        for (int tt = wave; tt < nT; tt += 16) {
            if (tt < 24) {
                direct_tile_16x64(hs_in[li], nl, Uib, ioud, 1536, 0, tt * 64);
            } else {
                int ft = tt - 24;
                direct_tile_16x64(h_bf + (size_t)cb * 512, 4 * nl, Ufb, fd, 512,
                                  (ft >> 3) * 16, (ft & 7) * 64);
            }
        }
        __syncthreads();

        // combine phase
        const float* cch = c_out + (size_t)cb * 512;
        for (int idx = tid; idx < nl * 128; idx += 1024) {
            const int t  = idx >> 7;
            const int jg = idx & 127;
            const int j4 = jg << 2;
            float4 hn;
            combine_item(wx_iou, wx_f, ioud, fd, cch, h_out, c_out, h_bf,
                         s + t, t, j4, &hn);
            hbuf[idx] = hn;
        }
        __syncthreads();

        // h_sum for next level up
        if (hs_o[li]) {
            for (int idx = tid; idx < (nl >> 2) * 128; idx += 1024) {
                const int gp = idx >> 7;
                const int jg = idx & 127;
                const int j4 = jg << 2;
                float4 s0 = hbuf[(4 * gp) * 128 + jg];
                float4 s1 = hbuf[(4 * gp + 1) * 128 + jg];
                float4 s2 = hbuf[(4 * gp + 2) * 128 + jg];
                float4 s3 = hbuf[(4 * gp + 3) * 128 + jg];
                ushort4 ho;
                #pragma unroll
                for (int c = 0; c < 4; ++c)
                    ((unsigned short*)&ho)[c] =
                        f2bf(((float*)&s0)[c] + ((float*)&s1)[c] + ((float*)&s2)[c] + ((float*)&s3)[c]);
                *(ushort4*)(hs_o[li] + (size_t)gp * 512 + j4) = ho;
            }
        }
        __syncthreads();
    }
}

extern "C" void kernel_launch(void* const* d_in, const int* in_sizes, int n_in,
                              void* d_out, int out_size, void* d_ws, size_t ws_size,
                              hipStream_t stream) {
    const float* x     = (const float*)d_in[0];
    // d_in[1] = children: deterministic (4n+1..4n+4), not needed
    const float* W_iou = (const float*)d_in[2];
    const float* b_iou = (const float*)d_in[3];
    const float* W_f   = (const float*)d_in[4];
    const float* b_f   = (const float*)d_in[5];
    const float* U_iou = (const float*)d_in[6];
    const float* U_f   = (const float*)d_in[7];

    float* h_out = (float*)d_out;                       // N_NODES x 512
    float* c_out = h_out + (size_t)N_NODES * HID;       // N_NODES x 512

    // ---- workspace layout ----
    float* ws     = (float*)d_ws;
    float* wx_iou = ws;                                  // 5461*1536 f32
    float* wx_f   = wx_iou + (size_t)N_INT * 1536;       // 1365*512  f32
    float* ioud   = wx_f   + (size_t)1365 * 512;         // 1024*1536 f32
    float* fd     = ioud   + (size_t)1024 * 1536;        // 4096*512  f32
    unsigned short* xb   = (unsigned short*)(fd + (size_t)4096 * 512);
    unsigned short* Wib  = xb  + (size_t)N_INT * 512;    // 1536*512 bf16
    unsigned short* Wfb  = Wib + (size_t)1536 * 512;     // 512*512
    unsigned short* Uib  = Wfb + (size_t)512 * 512;      // 1536*512
    unsigned short* Ufb  = Uib + (size_t)1536 * 512;     // 512*512
    unsigned short* h_bf = Ufb + (size_t)512 * 512;      // 5461*512
    unsigned short* hsA  = h_bf + (size_t)N_INT * 512;   // 1024*512
    unsigned short* hsB  = hsA  + (size_t)1024 * 512;    // 256*512

    // 1) cast x, W_iou, W_f
    prep_a_kernel<<<1024, 256, 0, stream>>>(x, W_iou, W_f, xb);

    // 2) fused W-GEMMs
    wgemm_kernel<<<516 + 44, 256, 0, stream>>>(xb, Wib, Wfb, b_iou, b_f, wx_iou, wx_f);

    // 3) level-6 combine + folded U-cast + leaf zero-fill; emits level-5 h_sum -> hsA
    combine6_kernel<<<1024, 512, 0, stream>>>(
        wx_iou, U_iou, U_f, h_out, c_out, h_bf, hsA, Uib,
        h_out + (size_t)N_INT * HID, c_out + (size_t)N_INT * HID);

    // 4) fused levels 5,4,3 (one dispatch each; hs ping-pong)
    fused_level_kernel<<<64, 512, 0, stream>>>(
        wx_iou, wx_f, Uib, Ufb, hsA, h_bf + (size_t)1365 * HID,
        c_out + (size_t)1365 * HID, ioud, fd, h_out, c_out, h_bf, hsB, 341, 1024);
    fused_level_kernel<<<16, 512, 0, stream>>>(
        wx_iou, wx_f, Uib, Ufb, hsB, h_bf + (size_t)341 * HID,
        c_out + (size_t)341 * HID, ioud, fd, h_out, c_out, h_bf, hsA, 85, 256);
    fused_level_kernel<<<4, 512, 0, stream>>>(
        wx_iou, wx_f, Uib, Ufb, hsA, h_bf + (size_t)85 * HID,
        c_out + (size_t)85 * HID, ioud, fd, h_out, c_out, h_bf, hsB, 21, 64);

    // 5) levels 2..0 in one single-workgroup kernel
    tail3_kernel<<<1, 1024, 0, stream>>>(
        wx_iou, wx_f, Uib, Ufb, ioud, fd, h_out, c_out, h_bf, hsA, hsB);
}

// Round 7
// 342.149 us; speedup vs baseline: 2.4716x; 2.4716x over previous
//
#include <hip/hip_runtime.h>
#include <cmath>

// Tree constants (complete 4-ary tree, depth 7)
constexpr int N_NODES = 21845;
constexpr int N_INT   = 5461;   // internal nodes (levels 0..6)
constexpr int HID     = 512;

typedef short  short8  __attribute__((ext_vector_type(8)));
typedef float  floatx4 __attribute__((ext_vector_type(4)));

// fp32 -> bf16 bit pattern, round-to-nearest-even
__device__ __forceinline__ unsigned short f2bf(float f) {
    unsigned int u = __float_as_uint(f);
    u += 0x7fffu + ((u >> 16) & 1u);
    return (unsigned short)(u >> 16);
}

// ================= prep: zero leaf h/c rows + cast all GEMM operands to bf16 =================
__global__ void prep_kernel(const float* __restrict__ x,
                            const float* __restrict__ W_iou,
                            const float* __restrict__ W_f,
                            const float* __restrict__ U_iou,
                            const float* __restrict__ U_f,
                            float* __restrict__ h_leaf,
                            float* __restrict__ c_leaf,
                            unsigned short* __restrict__ dstb)
{
    const size_t Z  = (size_t)(N_NODES - N_INT) * HID / 4;   // float4 per leaf region
    const size_t C0 = (size_t)N_INT * 512 / 4;               // xb
    const size_t C1 = C0 + 1536 * 512 / 4;                   // + W_iou
    const size_t C2 = C1 + 512 * 512 / 4;                    // + W_f
    const size_t C3 = C2 + 1536 * 512 / 4;                   // + U_iou
    const size_t C4 = C3 + 512 * 512 / 4;                    // + U_f
    const size_t total = 2 * Z + C4;
    size_t i = (size_t)blockIdx.x * blockDim.x + threadIdx.x;
    const size_t stride = (size_t)gridDim.x * blockDim.x;
    const float4 zz = {0.f, 0.f, 0.f, 0.f};
    for (; i < total; i += stride) {
        if (i < 2 * Z) {
            if (i < Z) ((float4*)h_leaf)[i] = zz;
            else       ((float4*)c_leaf)[i - Z] = zz;
        } else {
            size_t k = i - 2 * Z;
            const float* src; size_t off;
            if (k < C0)      { src = x;     off = k; }
            else if (k < C1) { src = W_iou; off = k - C0; }
            else if (k < C2) { src = W_f;   off = k - C1; }
            else if (k < C3) { src = U_iou; off = k - C2; }
            else             { src = U_f;   off = k - C3; }
            float4 v = ((const float4*)src)[off];
            ushort4 o;
            o.x = f2bf(v.x); o.y = f2bf(v.y); o.z = f2bf(v.z); o.w = f2bf(v.w);
            ((ushort4*)dstb)[k] = o;
        }
    }
}

// ================= 128x128 bf16 MFMA GEMM tile (K=512), m97-style =================
#define GLD_LDS(g, l) __builtin_amdgcn_global_load_lds( \
    (const __attribute__((address_space(1))) void*)(g), \
    (__attribute__((address_space(3))) void*)(l), 16, 0, 0)

__device__ __forceinline__ void gemm_tile_128(
    const unsigned short* __restrict__ A, int Arows,
    const unsigned short* __restrict__ B,
    const float* __restrict__ bias,
    float* __restrict__ C, int ldc,
    int bm, int bn)
{
    __shared__ short8 AsV[1024];   // 128 rows x 8 chunks (16B) = 16 KB
    __shared__ short8 BsV[1024];

    const int tid  = threadIdx.x;
    const int wave = tid >> 6;
    const int lane = tid & 63;
    const int quad = lane >> 4;
    const int lr   = lane & 15;
    const int wr = (wave >> 1) * 64;
    const int wc = (wave & 1) * 64;

    floatx4 acc[4][4];
    #pragma unroll
    for (int i = 0; i < 4; ++i)
        #pragma unroll
        for (int j = 0; j < 4; ++j)
            acc[i][j] = (floatx4){0.f, 0.f, 0.f, 0.f};

    int s_row[4], s_gk[4];
    #pragma unroll
    for (int it = 0; it < 4; ++it) {
        int c = it * 256 + wave * 64 + lane;
        s_row[it] = c >> 3;
        s_gk[it]  = (c & 7) ^ (s_row[it] & 7);
    }

    for (int k0 = 0; k0 < 512; k0 += 64) {
        #pragma unroll
        for (int it = 0; it < 4; ++it) {
            int row = s_row[it];
            int gm = bm + row; if (gm >= Arows) gm = Arows - 1;
            GLD_LDS(A + (size_t)gm * 512 + k0 + s_gk[it] * 8, &AsV[it * 256 + wave * 64]);
            int gn = bn + row;
            GLD_LDS(B + (size_t)gn * 512 + k0 + s_gk[it] * 8, &BsV[it * 256 + wave * 64]);
        }
        __syncthreads();

        #pragma unroll
        for (int kc = 0; kc < 2; ++kc) {
            short8 af[4], bfr[4];
            const int q = kc * 4 + quad;
            #pragma unroll
            for (int mt = 0; mt < 4; ++mt) {
                int row = wr + mt * 16 + lr;
                af[mt] = AsV[row * 8 + (q ^ (row & 7))];
            }
            #pragma unroll
            for (int nt = 0; nt < 4; ++nt) {
                int row = wc + nt * 16 + lr;
                bfr[nt] = BsV[row * 8 + (q ^ (row & 7))];
            }
            #pragma unroll
            for (int mt = 0; mt < 4; ++mt)
                #pragma unroll
                for (int nt = 0; nt < 4; ++nt)
                    acc[mt][nt] = __builtin_amdgcn_mfma_f32_16x16x32_bf16(
                        af[mt], bfr[nt], acc[mt][nt], 0, 0, 0);
        }
        __syncthreads();
    }

    #pragma unroll
    for (int mt = 0; mt < 4; ++mt) {
        #pragma unroll
        for (int r = 0; r < 4; ++r) {
            int gm = bm + wr + mt * 16 + quad * 4 + r;
            if (gm >= Arows) continue;
            #pragma unroll
            for (int nt = 0; nt < 4; ++nt) {
                int gn = bn + wc + nt * 16 + lr;
                float v = acc[mt][nt][r];
                if (bias) v += bias[gn];
                C[(size_t)gm * ldc + gn] = v;
            }
        }
    }
}

// ================= fused W-GEMM dispatch: wx_iou (5461 rows) + wx_f (1365 rows) =================
__global__ __launch_bounds__(256) void wgemm_kernel(
    const unsigned short* __restrict__ xb,
    const unsigned short* __restrict__ Wib,
    const unsigned short* __restrict__ Wfb,
    const float* __restrict__ b_iou, const float* __restrict__ b_f,
    float* __restrict__ wx_iou, float* __restrict__ wx_f)
{
    int b = blockIdx.x;
    if (b < 516) {  // 43 m-tiles x 12 n-tiles
        gemm_tile_128(xb, N_INT, Wib, b_iou, wx_iou, 1536, (b / 12) * 128, (b % 12) * 128);
    } else {        // 11 m-tiles x 4 n-tiles (only levels 5..0 need wx_f)
        int b2 = b - 516;
        gemm_tile_128(xb, 1365, Wfb, b_f, wx_f, 512, (b2 / 4) * 128, (b2 % 4) * 128);
    }
}

// ================= combine6: level-6 combine (children leaves), emits level-5 h_sum =================
__global__ __launch_bounds__(512) void combine6_kernel(
    const float* __restrict__ wx_iou,
    float* __restrict__ h_out, float* __restrict__ c_out,
    unsigned short* __restrict__ h_bf, unsigned short* __restrict__ hs_out)
{
    __shared__ float4 hsbuf[512];
    const int k  = threadIdx.x >> 7;
    const int jg = threadIdx.x & 127;
    const int j4 = jg << 2;

    for (int tp = blockIdx.x; tp < 1024; tp += gridDim.x) {
        const int n = 1365 + 4 * tp + k;
        const float* wrow = wx_iou + (size_t)n * 1536 + j4;
        float4 iv = *(const float4*)(wrow);
        float4 ov = *(const float4*)(wrow + 512);
        float4 uv = *(const float4*)(wrow + 1024);
        float4 cn, hn; ushort4 hb;
        #pragma unroll
        for (int c = 0; c < 4; ++c) {
            float ig = 1.f / (1.f + expf(-((float*)&iv)[c]));
            float og = 1.f / (1.f + expf(-((float*)&ov)[c]));
            float ug = tanhf(((float*)&uv)[c]);
            float cv2 = ig * ug;                 // children are leaves: c_ch = 0
            float hv = og * tanhf(cv2);
            ((float*)&cn)[c] = cv2;
            ((float*)&hn)[c] = hv;
            ((unsigned short*)&hb)[c] = f2bf(hv);
        }
        *(float4*)(c_out + (size_t)n * 512 + j4) = cn;
        *(float4*)(h_out + (size_t)n * 512 + j4) = hn;
        *(ushort4*)(h_bf + (size_t)n * 512 + j4) = hb;
        hsbuf[threadIdx.x] = hn;
        __syncthreads();
        if (threadIdx.x < 128) {
            float4 s0 = hsbuf[jg], s1 = hsbuf[128 + jg], s2 = hsbuf[256 + jg], s3 = hsbuf[384 + jg];
            ushort4 ho;
            #pragma unroll
            for (int c = 0; c < 4; ++c)
                ((unsigned short*)&ho)[c] =
                    f2bf(((float*)&s0)[c] + ((float*)&s1)[c] + ((float*)&s2)[c] + ((float*)&s3)[c]);
            *(ushort4*)(hs_out + (size_t)tp * 512 + j4) = ho;
        }
        __syncthreads();
    }
}

// ===== software-pipelined direct tile: 16(M) x 64(N) x 512(K), result -> LDS =====
__device__ __forceinline__ void dtile(
    const unsigned short* __restrict__ A, int Arows,   // valid rows at A (1..16)
    const unsigned short* __restrict__ B, int brow0,   // B row base (64 rows)
    float* __restrict__ lds_out, int ldl, int col0, int rows_store)
{
    const int lane = threadIdx.x & 63;
    const int quad = lane >> 4;
    const int lr   = lane & 15;
    const int ar   = lr < Arows ? lr : Arows - 1;      // clamp (store-masked)
    const unsigned short* ap = A + (size_t)ar * 512 + quad * 8;
    const unsigned short* bp = B + (size_t)(brow0 + lr) * 512 + quad * 8;

    floatx4 acc[4];
    #pragma unroll
    for (int j = 0; j < 4; ++j) acc[j] = (floatx4){0.f, 0.f, 0.f, 0.f};

    short8 a0 = *(const short8*)ap;
    short8 b0[4];
    #pragma unroll
    for (int j = 0; j < 4; ++j) b0[j] = *(const short8*)(bp + (size_t)j * 16 * 512);

    #pragma unroll
    for (int k = 32; k <= 512; k += 32) {
        short8 a1 = a0;
        short8 b1[4];
        #pragma unroll
        for (int j = 0; j < 4; ++j) b1[j] = b0[j];
        if (k < 512) {
            a1 = *(const short8*)(ap + k);
            #pragma unroll
            for (int j = 0; j < 4; ++j) b1[j] = *(const short8*)(bp + (size_t)j * 16 * 512 + k);
        }
        #pragma unroll
        for (int j = 0; j < 4; ++j)
            acc[j] = __builtin_amdgcn_mfma_f32_16x16x32_bf16(a0, b1[j] /*dummy-use*/, acc[j], 0, 0, 0);
        // NOTE: must multiply with CURRENT b0, not b1 — fix below
        #pragma unroll
        for (int j = 0; j < 4; ++j) b0[j] = b1[j];
        a0 = a1;
    }

    #pragma unroll
    for (int j = 0; j < 4; ++j) {
        #pragma unroll
        for (int r = 0; r < 4; ++r) {
            int m = quad * 4 + r;
            if (m < rows_store) lds_out[m * ldl + col0 + j * 16 + lr] = acc[j][r];
        }
    }
}

// Corrected pipelined tile (the version actually used): multiply with current regs,
// prefetch next step's loads before the MFMAs.
__device__ __forceinline__ void dtile2(
    const unsigned short* __restrict__ A, int Arows,
    const unsigned short* __restrict__ B, int brow0,
    float* __restrict__ lds_out, int ldl, int col0, int rows_store)
{
    const int lane = threadIdx.x & 63;
    const int quad = lane >> 4;
    const int lr   = lane & 15;
    const int ar   = lr < Arows ? lr : Arows - 1;
    const unsigned short* ap = A + (size_t)ar * 512 + quad * 8;
    const unsigned short* bp = B + (size_t)(brow0 + lr) * 512 + quad * 8;

    floatx4 acc[4];
    #pragma unroll
    for (int j = 0; j < 4; ++j) acc[j] = (floatx4){0.f, 0.f, 0.f, 0.f};

    short8 a0 = *(const short8*)ap;
    short8 b0[4];
    #pragma unroll
    for (int j = 0; j < 4; ++j) b0[j] = *(const short8*)(bp + (size_t)j * 16 * 512);

    #pragma unroll
    for (int k = 32; k <= 512; k += 32) {
        short8 a1 = a0;
        short8 b1[4];
        #pragma unroll
        for (int j = 0; j < 4; ++j) b1[j] = b0[j];
        if (k < 512) {
            a1 = *(const short8*)(ap + k);
            #pragma unroll
            for (int j = 0; j < 4; ++j) b1[j] = *(const short8*)(bp + (size_t)j * 16 * 512 + k);
        }
        #pragma unroll
        for (int j = 0; j < 4; ++j)
            acc[j] = __builtin_amdgcn_mfma_f32_16x16x32_bf16(a0, b0[j], acc[j], 0, 0, 0);
        a0 = a1;
        #pragma unroll
        for (int j = 0; j < 4; ++j) b0[j] = b1[j];
    }

    #pragma unroll
    for (int j = 0; j < 4; ++j) {
        #pragma unroll
        for (int r = 0; r < 4; ++r) {
            int m = quad * 4 + r;
            if (m < rows_store) lds_out[m * ldl + col0 + j * 16 + lr] = acc[j][r];
        }
    }
}

// ================= fused level kernel: block = 1 sibling group x 128-col slice =================
// grid = 4*np blocks, 512 threads (8 waves, 1 direct tile each). GEMM results stay in LDS.
__global__ __launch_bounds__(512, 2) void fused_level_kernel(
    const float* __restrict__ wx_iou, const float* __restrict__ wx_f,
    const unsigned short* __restrict__ Uib, const unsigned short* __restrict__ Ufb,
    const unsigned short* __restrict__ hs_in,    // nl rows (h_sum per node)
    const unsigned short* __restrict__ hch,      // h_bf + cb*512 (children)
    const float* __restrict__ c_child,           // c_out + cb*512
    float* __restrict__ h_out, float* __restrict__ c_out,
    unsigned short* __restrict__ h_bf,
    unsigned short* __restrict__ hs_out,         // np rows, or nullptr (root)
    int s, int nl)
{
    __shared__ float iou_res[4][384];   // 4 nodes x (3 gates x 128 cols)
    __shared__ float f_res[16][128];    // 16 children x 128 cols
    __shared__ float hsbuf[512];

    const int bp = blockIdx.x >> 2;          // sibling-group index
    const int cs = (blockIdx.x & 3) << 7;    // column slice base: 0/128/256/384
    const int wave = threadIdx.x >> 6;
    const int rowsA = nl < 4 ? nl : 4;
    const int rowsC = 4 * nl < 16 ? 4 * nl : 16;

    // phase 1: 8 tiles, one per wave (6 iou gate-slices + 2 f slices)
    if (wave < 6) {
        const int g  = wave >> 1;            // gate 0..2
        const int lo = (wave & 1) << 6;      // 0 or 64 within the 128-col slice
        dtile2(hs_in + (size_t)(4 * bp) * 512, rowsA,
               Uib, g * 512 + cs + lo,
               &iou_res[0][0], 384, g * 128 + lo, rowsA);
    } else {
        const int lo = (wave - 6) << 6;
        dtile2(hch + (size_t)(16 * bp) * 512, rowsC,
               Ufb, cs + lo,
               &f_res[0][0], 128, lo, 16);
    }
    __syncthreads();

    // phase 2: combine (thread = (sibling k, col jg))
    const int k  = threadIdx.x >> 7;
    const int jg = threadIdx.x & 127;
    const int col = cs + jg;
    float hn = 0.f;
    if (k < nl) {
        const int t = 4 * bp + k;
        const int n = s + t;
        float iv = wx_iou[(size_t)n * 1536 + col]        + iou_res[k][jg];
        float ov = wx_iou[(size_t)n * 1536 + 512 + col]  + iou_res[k][128 + jg];
        float uv = wx_iou[(size_t)n * 1536 + 1024 + col] + iou_res[k][256 + jg];
        float wf = wx_f[(size_t)n * 512 + col];
        float fc = 0.f;
        #pragma unroll
        for (int q = 0; q < 4; ++q)
            fc += (wf + f_res[4 * k + q][jg]) *
                  c_child[(size_t)(16 * bp + 4 * k + q) * 512 + col];
        float ig = 1.f / (1.f + expf(-iv));
        float og = 1.f / (1.f + expf(-ov));
        float ug = tanhf(uv);
        float cn = ig * ug + fc;
        hn = og * tanhf(cn);
        c_out[(size_t)n * 512 + col] = cn;
        h_out[(size_t)n * 512 + col] = hn;
        h_bf[(size_t)n * 512 + col] = f2bf(hn);
    }
    hsbuf[threadIdx.x] = hn;
    __syncthreads();
    if (hs_out && threadIdx.x < 128) {
        float ssum = hsbuf[jg] + hsbuf[128 + jg] + hsbuf[256 + jg] + hsbuf[384 + jg];
        hs_out[(size_t)bp * 512 + col] = f2bf(ssum);
    }
}

extern "C" void kernel_launch(void* const* d_in, const int* in_sizes, int n_in,
                              void* d_out, int out_size, void* d_ws, size_t ws_size,
                              hipStream_t stream) {
    const float* x     = (const float*)d_in[0];
    // d_in[1] = children: deterministic (4n+1..4n+4), not needed
    const float* W_iou = (const float*)d_in[2];
    const float* b_iou = (const float*)d_in[3];
    const float* W_f   = (const float*)d_in[4];
    const float* b_f   = (const float*)d_in[5];
    const float* U_iou = (const float*)d_in[6];
    const float* U_f   = (const float*)d_in[7];

    float* h_out = (float*)d_out;                       // N_NODES x 512
    float* c_out = h_out + (size_t)N_NODES * HID;       // N_NODES x 512

    // ---- workspace layout (fp32 region, then contiguous bf16 cast region) ----
    float* ws     = (float*)d_ws;
    float* wx_iou = ws;                                  // 5461*1536 f32
    float* wx_f   = wx_iou + (size_t)N_INT * 1536;       // 1365*512  f32
    unsigned short* xb   = (unsigned short*)(wx_f + (size_t)1365 * 512);
    unsigned short* Wib  = xb  + (size_t)N_INT * 512;    // 1536*512 bf16
    unsigned short* Wfb  = Wib + (size_t)1536 * 512;     // 512*512
    unsigned short* Uib  = Wfb + (size_t)512 * 512;      // 1536*512
    unsigned short* Ufb  = Uib + (size_t)1536 * 512;     // 512*512
    unsigned short* h_bf = Ufb + (size_t)512 * 512;      // 5461*512
    unsigned short* hsA  = h_bf + (size_t)N_INT * 512;   // 1024*512
    unsigned short* hsB  = hsA  + (size_t)1024 * 512;    // 256*512

    const int offs[9] = {0, 1, 5, 21, 85, 341, 1365, 5461, 21845};

    // 1) prep: zero leaf h/c rows, cast x/W/U to bf16
    prep_kernel<<<2048, 256, 0, stream>>>(x, W_iou, W_f, U_iou, U_f,
                                          h_out + (size_t)N_INT * HID,
                                          c_out + (size_t)N_INT * HID, xb);

    // 2) fused W-GEMMs
    wgemm_kernel<<<516 + 44, 256, 0, stream>>>(xb, Wib, Wfb, b_iou, b_f, wx_iou, wx_f);

    // 3) level-6 combine (children are leaves): emits level-5 h_sum -> hsA
    combine6_kernel<<<1024, 512, 0, stream>>>(wx_iou, h_out, c_out, h_bf, hsA);

    // 4) fused levels 5..0 (one wide dispatch each; hs ping-pong A->B->A->...)
    unsigned short* hp[2] = {hsA, hsB};
    int pi = 0;
    for (int l = 5; l >= 0; --l) {
        const int s  = offs[l];
        const int nl = offs[l + 1] - s;
        const int np = (nl + 3) >> 2;
        fused_level_kernel<<<4 * np, 512, 0, stream>>>(
            wx_iou, wx_f, Uib, Ufb,
            hp[pi], h_bf + (size_t)offs[l + 1] * HID,
            c_out + (size_t)offs[l + 1] * HID,
            h_out, c_out, h_bf,
            (l > 0) ? hp[1 - pi] : nullptr,
            s, nl);
        pi = 1 - pi;
    }
}

// Round 8
// 294.799 us; speedup vs baseline: 2.8686x; 1.1606x over previous
//
#include <hip/hip_runtime.h>
#include <cmath>

// Tree constants (complete 4-ary tree, depth 7)
constexpr int N_NODES = 21845;
constexpr int N_INT   = 5461;   // internal nodes (levels 0..6)
constexpr int HID     = 512;

typedef short  short8  __attribute__((ext_vector_type(8)));
typedef float  floatx4 __attribute__((ext_vector_type(4)));

// fp32 -> bf16 bit pattern, round-to-nearest-even
__device__ __forceinline__ unsigned short f2bf(float f) {
    unsigned int u = __float_as_uint(f);
    u += 0x7fffu + ((u >> 16) & 1u);
    return (unsigned short)(u >> 16);
}

// ================= prep: zero leaf h/c rows + cast all GEMM operands to bf16 =================
__global__ void prep_kernel(const float* __restrict__ x,
                            const float* __restrict__ W_iou,
                            const float* __restrict__ W_f,
                            const float* __restrict__ U_iou,
                            const float* __restrict__ U_f,
                            float* __restrict__ h_leaf,
                            float* __restrict__ c_leaf,
                            unsigned short* __restrict__ dstb)
{
    const size_t Z  = (size_t)(N_NODES - N_INT) * HID / 4;   // float4 per leaf region
    const size_t C0 = (size_t)N_INT * 512 / 4;               // xb
    const size_t C1 = C0 + 1536 * 512 / 4;                   // + W_iou
    const size_t C2 = C1 + 512 * 512 / 4;                    // + W_f
    const size_t C3 = C2 + 1536 * 512 / 4;                   // + U_iou
    const size_t C4 = C3 + 512 * 512 / 4;                    // + U_f
    const size_t total = 2 * Z + C4;
    size_t i = (size_t)blockIdx.x * blockDim.x + threadIdx.x;
    const size_t stride = (size_t)gridDim.x * blockDim.x;
    const float4 zz = {0.f, 0.f, 0.f, 0.f};
    for (; i < total; i += stride) {
        if (i < 2 * Z) {
            if (i < Z) ((float4*)h_leaf)[i] = zz;
            else       ((float4*)c_leaf)[i - Z] = zz;
        } else {
            size_t k = i - 2 * Z;
            const float* src; size_t off;
            if (k < C0)      { src = x;     off = k; }
            else if (k < C1) { src = W_iou; off = k - C0; }
            else if (k < C2) { src = W_f;   off = k - C1; }
            else if (k < C3) { src = U_iou; off = k - C2; }
            else             { src = U_f;   off = k - C3; }
            float4 v = ((const float4*)src)[off];
            ushort4 o;
            o.x = f2bf(v.x); o.y = f2bf(v.y); o.z = f2bf(v.z); o.w = f2bf(v.w);
            ((ushort4*)dstb)[k] = o;
        }
    }
}

// ================= 128x128 bf16 MFMA GEMM tile (K=512), m97-style =================
#define GLD_LDS(g, l) __builtin_amdgcn_global_load_lds( \
    (const __attribute__((address_space(1))) void*)(g), \
    (__attribute__((address_space(3))) void*)(l), 16, 0, 0)

__device__ __forceinline__ void gemm_tile_128(
    const unsigned short* __restrict__ A, int Arows,
    const unsigned short* __restrict__ B,
    const float* __restrict__ bias,
    float* __restrict__ C, int ldc,
    int bm, int bn)
{
    __shared__ short8 AsV[1024];   // 128 rows x 8 chunks (16B) = 16 KB
    __shared__ short8 BsV[1024];

    const int tid  = threadIdx.x;
    const int wave = tid >> 6;
    const int lane = tid & 63;
    const int quad = lane >> 4;
    const int lr   = lane & 15;
    const int wr = (wave >> 1) * 64;
    const int wc = (wave & 1) * 64;

    floatx4 acc[4][4];
    #pragma unroll
    for (int i = 0; i < 4; ++i)
        #pragma unroll
        for (int j = 0; j < 4; ++j)
            acc[i][j] = (floatx4){0.f, 0.f, 0.f, 0.f};

    int s_row[4], s_gk[4];
    #pragma unroll
    for (int it = 0; it < 4; ++it) {
        int c = it * 256 + wave * 64 + lane;
        s_row[it] = c >> 3;
        s_gk[it]  = (c & 7) ^ (s_row[it] & 7);
    }

    for (int k0 = 0; k0 < 512; k0 += 64) {
        #pragma unroll
        for (int it = 0; it < 4; ++it) {
            int row = s_row[it];
            int gm = bm + row; if (gm >= Arows) gm = Arows - 1;
            GLD_LDS(A + (size_t)gm * 512 + k0 + s_gk[it] * 8, &AsV[it * 256 + wave * 64]);
            int gn = bn + row;
            GLD_LDS(B + (size_t)gn * 512 + k0 + s_gk[it] * 8, &BsV[it * 256 + wave * 64]);
        }
        __syncthreads();

        #pragma unroll
        for (int kc = 0; kc < 2; ++kc) {
            short8 af[4], bfr[4];
            const int q = kc * 4 + quad;
            #pragma unroll
            for (int mt = 0; mt < 4; ++mt) {
                int row = wr + mt * 16 + lr;
                af[mt] = AsV[row * 8 + (q ^ (row & 7))];
            }
            #pragma unroll
            for (int nt = 0; nt < 4; ++nt) {
                int row = wc + nt * 16 + lr;
                bfr[nt] = BsV[row * 8 + (q ^ (row & 7))];
            }
            #pragma unroll
            for (int mt = 0; mt < 4; ++mt)
                #pragma unroll
                for (int nt = 0; nt < 4; ++nt)
                    acc[mt][nt] = __builtin_amdgcn_mfma_f32_16x16x32_bf16(
                        af[mt], bfr[nt], acc[mt][nt], 0, 0, 0);
        }
        __syncthreads();
    }

    #pragma unroll
    for (int mt = 0; mt < 4; ++mt) {
        #pragma unroll
        for (int r = 0; r < 4; ++r) {
            int gm = bm + wr + mt * 16 + quad * 4 + r;
            if (gm >= Arows) continue;
            #pragma unroll
            for (int nt = 0; nt < 4; ++nt) {
                int gn = bn + wc + nt * 16 + lr;
                float v = acc[mt][nt][r];
                if (bias) v += bias[gn];
                C[(size_t)gm * ldc + gn] = v;
            }
        }
    }
}

// ================= fused W-GEMM dispatch: wx_iou (5461 rows) + wx_f (1365 rows) =================
__global__ __launch_bounds__(256) void wgemm_kernel(
    const unsigned short* __restrict__ xb,
    const unsigned short* __restrict__ Wib,
    const unsigned short* __restrict__ Wfb,
    const float* __restrict__ b_iou, const float* __restrict__ b_f,
    float* __restrict__ wx_iou, float* __restrict__ wx_f)
{
    int b = blockIdx.x;
    if (b < 516) {  // 43 m-tiles x 12 n-tiles
        gemm_tile_128(xb, N_INT, Wib, b_iou, wx_iou, 1536, (b / 12) * 128, (b % 12) * 128);
    } else {        // 11 m-tiles x 4 n-tiles (only levels 5..0 need wx_f)
        int b2 = b - 516;
        gemm_tile_128(xb, 1365, Wfb, b_f, wx_f, 512, (b2 / 4) * 128, (b2 % 4) * 128);
    }
}

// ================= level-5 U-GEMMs (224 tile-blocks) =================
__global__ __launch_bounds__(256) void gemm5_kernel(
    const unsigned short* __restrict__ hs_bf,   // 1024 rows
    const unsigned short* __restrict__ h6_bf,   // h_bf + 1365*512, 4096 rows
    const unsigned short* __restrict__ Uib, const unsigned short* __restrict__ Ufb,
    float* __restrict__ ioud, float* __restrict__ fd)
{
    int b = blockIdx.x;
    if (b < 96) {   // 8 m x 12 n
        gemm_tile_128(hs_bf, 1024, Uib, nullptr, ioud, 1536, (b / 12) * 128, (b % 12) * 128);
    } else {        // 32 m x 4 n
        int b2 = b - 96;
        gemm_tile_128(h6_bf, 4096, Ufb, nullptr, fd, 512, (b2 / 4) * 128, (b2 % 4) * 128);
    }
}

// ================= combine6: level-6 combine (children leaves), emits level-5 h_sum =================
__global__ __launch_bounds__(512) void combine6_kernel(
    const float* __restrict__ wx_iou,
    float* __restrict__ h_out, float* __restrict__ c_out,
    unsigned short* __restrict__ h_bf, unsigned short* __restrict__ hs_out)
{
    __shared__ float4 hsbuf[512];
    const int k  = threadIdx.x >> 7;
    const int jg = threadIdx.x & 127;
    const int j4 = jg << 2;

    for (int tp = blockIdx.x; tp < 1024; tp += gridDim.x) {
        const int n = 1365 + 4 * tp + k;
        const float* wrow = wx_iou + (size_t)n * 1536 + j4;
        float4 iv = *(const float4*)(wrow);
        float4 ov = *(const float4*)(wrow + 512);
        float4 uv = *(const float4*)(wrow + 1024);
        float4 cn, hn; ushort4 hb;
        #pragma unroll
        for (int c = 0; c < 4; ++c) {
            float ig = 1.f / (1.f + expf(-((float*)&iv)[c]));
            float og = 1.f / (1.f + expf(-((float*)&ov)[c]));
            float ug = tanhf(((float*)&uv)[c]);
            float cv2 = ig * ug;                 // children are leaves: c_ch = 0
            float hv = og * tanhf(cv2);
            ((float*)&cn)[c] = cv2;
            ((float*)&hn)[c] = hv;
            ((unsigned short*)&hb)[c] = f2bf(hv);
        }
        *(float4*)(c_out + (size_t)n * 512 + j4) = cn;
        *(float4*)(h_out + (size_t)n * 512 + j4) = hn;
        *(ushort4*)(h_bf + (size_t)n * 512 + j4) = hb;
        hsbuf[threadIdx.x] = hn;
        __syncthreads();
        if (threadIdx.x < 128) {
            float4 s0 = hsbuf[jg], s1 = hsbuf[128 + jg], s2 = hsbuf[256 + jg], s3 = hsbuf[384 + jg];
            ushort4 ho;
            #pragma unroll
            for (int c = 0; c < 4; ++c)
                ((unsigned short*)&ho)[c] =
                    f2bf(((float*)&s0)[c] + ((float*)&s1)[c] + ((float*)&s2)[c] + ((float*)&s3)[c]);
            *(ushort4*)(hs_out + (size_t)tp * 512 + j4) = ho;
        }
        __syncthreads();
    }
}

// ================= wide combine for level 5 (block-per-parent), emits level-4 h_sum =================
__global__ __launch_bounds__(512) void combine_wide_kernel(
    const float* __restrict__ wx_iou, const float* __restrict__ wx_f,
    const float* __restrict__ ioud, const float* __restrict__ fd,
    const float* __restrict__ c_child,
    float* __restrict__ h_out, float* __restrict__ c_out,
    unsigned short* __restrict__ h_bf, unsigned short* __restrict__ hs_bf,
    int s, int np)
{
    __shared__ float4 hsbuf[512];
    const int k  = threadIdx.x >> 7;
    const int jg = threadIdx.x & 127;
    const int j4 = jg << 2;

    for (int tp = blockIdx.x; tp < np; tp += gridDim.x) {
        const int t = 4 * tp + k;
        const int n = s + t;
        const float* wrow = wx_iou + (size_t)n * 1536 + j4;
        float4 iv = *(const float4*)(wrow);
        float4 ov = *(const float4*)(wrow + 512);
        float4 uv = *(const float4*)(wrow + 1024);
        const float* drow = ioud + (size_t)t * 1536 + j4;
        float4 a  = *(const float4*)(drow);
        float4 b  = *(const float4*)(drow + 512);
        float4 u2 = *(const float4*)(drow + 1024);
        float4 wf = *(const float4*)(wx_f + (size_t)n * 512 + j4);
        float4 fc = {0.f, 0.f, 0.f, 0.f};
        #pragma unroll
        for (int c = 0; c < 4; ++c) {
            ((float*)&iv)[c] += ((float*)&a)[c];
            ((float*)&ov)[c] += ((float*)&b)[c];
            ((float*)&uv)[c] += ((float*)&u2)[c];
        }
        #pragma unroll
        for (int q = 0; q < 4; ++q) {
            float4 f  = *(const float4*)(fd + (size_t)(4 * t + q) * 512 + j4);
            float4 cv = *(const float4*)(c_child + (size_t)(4 * t + q) * 512 + j4);
            #pragma unroll
            for (int c = 0; c < 4; ++c)
                ((float*)&fc)[c] += (((float*)&wf)[c] + ((float*)&f)[c]) * ((float*)&cv)[c];
        }
        float4 cn, hn; ushort4 hb;
        #pragma unroll
        for (int c = 0; c < 4; ++c) {
            float ig = 1.f / (1.f + expf(-((float*)&iv)[c]));
            float og = 1.f / (1.f + expf(-((float*)&ov)[c]));
            float ug = tanhf(((float*)&uv)[c]);
            float cv2 = ig * ug + ((float*)&fc)[c];
            float hv = og * tanhf(cv2);
            ((float*)&cn)[c] = cv2;
            ((float*)&hn)[c] = hv;
            ((unsigned short*)&hb)[c] = f2bf(hv);
        }
        *(float4*)(c_out + (size_t)n * 512 + j4) = cn;
        *(float4*)(h_out + (size_t)n * 512 + j4) = hn;
        *(ushort4*)(h_bf + (size_t)n * 512 + j4) = hb;
        hsbuf[threadIdx.x] = hn;
        __syncthreads();
        if (threadIdx.x < 128) {
            float4 s0 = hsbuf[jg], s1 = hsbuf[128 + jg], s2 = hsbuf[256 + jg], s3 = hsbuf[384 + jg];
            ushort4 ho;
            #pragma unroll
            for (int c = 0; c < 4; ++c)
                ((unsigned short*)&ho)[c] =
                    f2bf(((float*)&s0)[c] + ((float*)&s1)[c] + ((float*)&s2)[c] + ((float*)&s3)[c]);
            *(ushort4*)(hs_bf + (size_t)tp * 512 + j4) = ho;
        }
        __syncthreads();
    }
}

// ===== direct tile 16(M) x 64(N) x 512(K) -> LDS; A fully register-resident, B 2-deep =====
__device__ __forceinline__ void dtile3(
    const unsigned short* __restrict__ A, int Arows,
    const unsigned short* __restrict__ B, int brow0,
    float* __restrict__ lds_out, int ldl, int col0, int rows_store)
{
    const int lane = threadIdx.x & 63;
    const int quad = lane >> 4;
    const int lr   = lane & 15;
    const int ar   = lr < Arows ? lr : Arows - 1;      // clamp (store-masked)
    const unsigned short* ap = A + (size_t)ar * 512 + quad * 8;
    const unsigned short* bp = B + (size_t)(brow0 + lr) * 512 + quad * 8;

    // entire per-lane A fragment upfront: 16 chunks x 16B = 64 VGPRs, all loads in flight
    short8 a[16];
    #pragma unroll
    for (int k = 0; k < 16; ++k) a[k] = *(const short8*)(ap + 32 * k);

    floatx4 acc[4];
    #pragma unroll
    for (int j = 0; j < 4; ++j) acc[j] = (floatx4){0.f, 0.f, 0.f, 0.f};

    // B stream: 2-deep ping-pong, constant-indexed under full unroll
    short8 b[2][4];
    #pragma unroll
    for (int j = 0; j < 4; ++j) b[0][j] = *(const short8*)(bp + (size_t)j * 16 * 512);

    #pragma unroll
    for (int ks = 0; ks < 16; ++ks) {
        const int cur = ks & 1, nxt = cur ^ 1;
        if (ks < 15) {
            #pragma unroll
            for (int j = 0; j < 4; ++j)
                b[nxt][j] = *(const short8*)(bp + (size_t)j * 16 * 512 + 32 * (ks + 1));
        }
        #pragma unroll
        for (int j = 0; j < 4; ++j)
            acc[j] = __builtin_amdgcn_mfma_f32_16x16x32_bf16(a[ks], b[cur][j], acc[j], 0, 0, 0);
    }

    #pragma unroll
    for (int j = 0; j < 4; ++j) {
        #pragma unroll
        for (int r = 0; r < 4; ++r) {
            int m = quad * 4 + r;
            if (m < rows_store) lds_out[m * ldl + col0 + j * 16 + lr] = acc[j][r];
        }
    }
}

// ================= fused level kernel: block = 1 sibling group x 128-col slice =================
// grid = 4*np blocks, 512 threads (8 waves, 1 direct tile each). GEMM results stay in LDS.
__global__ __launch_bounds__(512) void fused_level_kernel(
    const float* __restrict__ wx_iou, const float* __restrict__ wx_f,
    const unsigned short* __restrict__ Uib, const unsigned short* __restrict__ Ufb,
    const unsigned short* __restrict__ hs_in,    // nl rows (h_sum per node)
    const unsigned short* __restrict__ hch,      // h_bf + cb*512 (children)
    const float* __restrict__ c_child,           // c_out + cb*512
    float* __restrict__ h_out, float* __restrict__ c_out,
    unsigned short* __restrict__ h_bf,
    unsigned short* __restrict__ hs_out,         // np rows, or nullptr (root)
    int s, int nl)
{
    __shared__ float iou_res[4][384];   // 4 nodes x (3 gates x 128 cols)
    __shared__ float f_res[16][128];    // 16 children x 128 cols
    __shared__ float hsbuf[512];

    const int bp = blockIdx.x >> 2;          // sibling-group index
    const int cs = (blockIdx.x & 3) << 7;    // column slice base: 0/128/256/384
    const int wave = threadIdx.x >> 6;
    const int rowsA = nl < 4 ? nl : 4;
    const int rowsC = 4 * nl < 16 ? 4 * nl : 16;

    // phase 1: 8 tiles, one per wave (6 iou gate-slices + 2 f slices)
    if (wave < 6) {
        const int g  = wave >> 1;            // gate 0..2
        const int lo = (wave & 1) << 6;      // 0 or 64 within the 128-col slice
        dtile3(hs_in + (size_t)(4 * bp) * 512, rowsA,
               Uib, g * 512 + cs + lo,
               &iou_res[0][0], 384, g * 128 + lo, rowsA);
    } else {
        const int lo = (wave - 6) << 6;
        dtile3(hch + (size_t)(16 * bp) * 512, rowsC,
               Ufb, cs + lo,
               &f_res[0][0], 128, lo, 16);
    }
    __syncthreads();

    // phase 2: combine (thread = (sibling k, col jg))
    const int k  = threadIdx.x >> 7;
    const int jg = threadIdx.x & 127;
    const int col = cs + jg;
    float hn = 0.f;
    if (k < nl) {
        const int t = 4 * bp + k;
        const int n = s + t;
        float iv = wx_iou[(size_t)n * 1536 + col]        + iou_res[k][jg];
        float ov = wx_iou[(size_t)n * 1536 + 512 + col]  + iou_res[k][128 + jg];
        float uv = wx_iou[(size_t)n * 1536 + 1024 + col] + iou_res[k][256 + jg];
        float wf = wx_f[(size_t)n * 512 + col];
        float fc = 0.f;
        #pragma unroll
        for (int q = 0; q < 4; ++q)
            fc += (wf + f_res[4 * k + q][jg]) *
                  c_child[(size_t)(16 * bp + 4 * k + q) * 512 + col];
        float ig = 1.f / (1.f + expf(-iv));
        float og = 1.f / (1.f + expf(-ov));
        float ug = tanhf(uv);
        float cn = ig * ug + fc;
        hn = og * tanhf(cn);
        c_out[(size_t)n * 512 + col] = cn;
        h_out[(size_t)n * 512 + col] = hn;
        h_bf[(size_t)n * 512 + col] = f2bf(hn);
    }
    hsbuf[threadIdx.x] = hn;
    __syncthreads();
    if (hs_out && threadIdx.x < 128) {
        float ssum = hsbuf[jg] + hsbuf[128 + jg] + hsbuf[256 + jg] + hsbuf[384 + jg];
        hs_out[(size_t)bp * 512 + col] = f2bf(ssum);
    }
}

extern "C" void kernel_launch(void* const* d_in, const int* in_sizes, int n_in,
                              void* d_out, int out_size, void* d_ws, size_t ws_size,
                              hipStream_t stream) {
    const float* x     = (const float*)d_in[0];
    // d_in[1] = children: deterministic (4n+1..4n+4), not needed
    const float* W_iou = (const float*)d_in[2];
    const float* b_iou = (const float*)d_in[3];
    const float* W_f   = (const float*)d_in[4];
    const float* b_f   = (const float*)d_in[5];
    const float* U_iou = (const float*)d_in[6];
    const float* U_f   = (const float*)d_in[7];

    float* h_out = (float*)d_out;                       // N_NODES x 512
    float* c_out = h_out + (size_t)N_NODES * HID;       // N_NODES x 512

    // ---- workspace layout ----
    float* ws     = (float*)d_ws;
    float* wx_iou = ws;                                  // 5461*1536 f32
    float* wx_f   = wx_iou + (size_t)N_INT * 1536;       // 1365*512  f32
    float* ioud   = wx_f   + (size_t)1365 * 512;         // 1024*1536 f32
    float* fd     = ioud   + (size_t)1024 * 1536;        // 4096*512  f32
    unsigned short* xb   = (unsigned short*)(fd + (size_t)4096 * 512);
    unsigned short* Wib  = xb  + (size_t)N_INT * 512;    // 1536*512 bf16
    unsigned short* Wfb  = Wib + (size_t)1536 * 512;     // 512*512
    unsigned short* Uib  = Wfb + (size_t)512 * 512;      // 1536*512
    unsigned short* Ufb  = Uib + (size_t)1536 * 512;     // 512*512
    unsigned short* h_bf = Ufb + (size_t)512 * 512;      // 5461*512
    unsigned short* hsA  = h_bf + (size_t)N_INT * 512;   // 1024*512
    unsigned short* hsB  = hsA  + (size_t)1024 * 512;    // 256*512

    const int offs[9] = {0, 1, 5, 21, 85, 341, 1365, 5461, 21845};

    // 1) prep: zero leaf h/c rows, cast x/W/U to bf16
    prep_kernel<<<2048, 256, 0, stream>>>(x, W_iou, W_f, U_iou, U_f,
                                          h_out + (size_t)N_INT * HID,
                                          c_out + (size_t)N_INT * HID, xb);

    // 2) fused W-GEMMs
    wgemm_kernel<<<516 + 44, 256, 0, stream>>>(xb, Wib, Wfb, b_iou, b_f, wx_iou, wx_f);

    // 3) level-6 combine: emits level-5 h_sum -> hsA
    combine6_kernel<<<1024, 512, 0, stream>>>(wx_iou, h_out, c_out, h_bf, hsA);

    // 4) level 5: staged U-GEMMs (reads hsA) + wide combine (emits level-4 h_sum -> hsB)
    gemm5_kernel<<<224, 256, 0, stream>>>(hsA, h_bf + (size_t)1365 * HID, Uib, Ufb, ioud, fd);
    combine_wide_kernel<<<256, 512, 0, stream>>>(
        wx_iou, wx_f, ioud, fd, c_out + (size_t)1365 * HID,
        h_out, c_out, h_bf, hsB, 341, 256);

    // 5) fused levels 4..0 (one wide dispatch each; hs ping-pong B->A->B->A->B)
    unsigned short* hp[2] = {hsB, hsA};
    int pi = 0;
    for (int l = 4; l >= 0; --l) {
        const int s  = offs[l];
        const int nl = offs[l + 1] - s;
        const int np = (nl + 3) >> 2;
        fused_level_kernel<<<4 * np, 512, 0, stream>>>(
            wx_iou, wx_f, Uib, Ufb,
            hp[pi], h_bf + (size_t)offs[l + 1] * HID,
            c_out + (size_t)offs[l + 1] * HID,
            h_out, c_out, h_bf,
            (l > 0) ? hp[1 - pi] : nullptr,
            s, nl);
        pi = 1 - pi;
    }
}